// Round 8
// baseline (588.495 us; speedup 1.0000x reference)
//
#include <hip/hip_runtime.h>
#include <hip/hip_bf16.h>
#include <stdint.h>

#define R_TOT   131072
#define D_IN    1024
#define N_CLS   81
#define N_BOX   320
#define N_H     256
#define N1_USED 657
#define N1_PAD  672

typedef __attribute__((ext_vector_type(8))) short short8;
typedef __attribute__((ext_vector_type(4))) float f32x4;

__device__ __forceinline__ unsigned short f2bf(float f) {
  union { float f; unsigned u; } v; v.f = f;
  unsigned r = v.u + 0x7FFFu + ((v.u >> 16) & 1u);
  return (unsigned short)(r >> 16);
}

__device__ __forceinline__ short8 cvt8(float4 a, float4 b) {
  short8 v;
  v[0] = (short)f2bf(a.x); v[1] = (short)f2bf(a.y);
  v[2] = (short)f2bf(a.z); v[3] = (short)f2bf(a.w);
  v[4] = (short)f2bf(b.x); v[5] = (short)f2bf(b.y);
  v[6] = (short)f2bf(b.z); v[7] = (short)f2bf(b.w);
  return v;
}

__device__ __forceinline__ void async_lds16(void* lds, const void* g) {
  __builtin_amdgcn_global_load_lds(
      (const __attribute__((address_space(1))) unsigned int*)g,
      (__attribute__((address_space(3))) unsigned int*)lds, 16, 0, 0);
}

// ---------------- prep: pack W_big into K-panels [32][672][32] bf16 ----------------
__global__ void prep_w1(const float* __restrict__ Wc, const float* __restrict__ Wb,
                        const float* __restrict__ W1, unsigned short* __restrict__ Wp)
{
  int idx = blockIdx.x * 256 + threadIdx.x;      // < 672*1024
  int p   = idx / (N1_PAD * 32);
  int rem = idx % (N1_PAD * 32);
  int n   = rem >> 5;
  int kk  = rem & 31;
  int k   = p * 32 + kk;
  float w = 0.f;
  if (n < N_CLS)               w = Wc[(size_t)n * D_IN + k];
  else if (n < N_CLS + N_BOX)  w = Wb[(size_t)(n - N_CLS) * D_IN + k];
  else if (n < N1_USED)        w = W1[(size_t)(n - (N_CLS + N_BOX)) * D_IN + k];
  Wp[idx] = f2bf(w);
}

__global__ void prep_w23(const float* __restrict__ W2, const float* __restrict__ W3,
                         unsigned short* __restrict__ W2b, unsigned short* __restrict__ W3b)
{
  int idx = blockIdx.x * 256 + threadIdx.x;      // < 131072
  if (idx < 65536) W2b[idx] = f2bf(W2[idx]);
  else             W3b[idx - 65536] = f2bf(W3[idx - 65536]);
}

// ---------------- GEMM1: 128(M) x 672(N), K=1024, M-only grid ----------------
// block = 896 threads (14 waves, 2x7); wave (wr,wc): rows [wr*64,+64), cols [wc*96,+96)
__global__ __launch_bounds__(896, 1) void g1_kernel(
    const float* __restrict__ x, const unsigned short* __restrict__ Wp,
    const float* __restrict__ b_cls, const float* __restrict__ b_box,
    const float* __restrict__ b1,
    float* __restrict__ scores, float* __restrict__ deltas,
    unsigned short* __restrict__ h1)
{
  __shared__ __attribute__((aligned(16))) unsigned short As[2][128 * 32];   // 8 KB x2
  __shared__ __attribute__((aligned(16))) unsigned short Bs[2][N1_PAD * 32]; // 43 KB x2

  const int tid  = threadIdx.x;
  const int wave = tid >> 6;
  const int lane = tid & 63;
  const int wr   = wave / 7;          // 0..1
  const int wc   = wave % 7;          // 0..6
  const int m0   = blockIdx.x * 128;

  f32x4 acc[4][6];
#pragma unroll
  for (int i = 0; i < 4; ++i)
#pragma unroll
    for (int j = 0; j < 6; ++j)
      acc[i][j] = (f32x4){0.f, 0.f, 0.f, 0.f};

  // ---- prologue: stage k-step 0 into buffer 0 ----
  {
#pragma unroll
    for (int i = 0; i < 3; ++i) {
      int chunk = tid + i * 896;                 // 0..2687
      async_lds16((char*)&Bs[0][0] + chunk * 16, (const char*)Wp + chunk * 16);
    }
    if (tid < 512) {
      int row = tid >> 2, kq = tid & 3;          // rows 0..127
      const float* src = x + (size_t)(m0 + row) * D_IN + kq * 8;
      float4 f0 = *(const float4*)src;
      float4 f1 = *(const float4*)(src + 4);
      *(short8*)&As[0][row * 32 + kq * 8] = cvt8(f0, f1);
    }
  }
  __syncthreads();

  const int lr = lane & 15;
  const int lk = (lane >> 4) * 8;

  for (int kp = 0; kp < 32; ++kp) {
    const int cur = kp & 1;
    const int nxt = cur ^ 1;
    const bool last = (kp == 31);

    float4 fa0, fa1;
    if (!last) {
      if (tid < 512) {                            // A: global -> reg (fp32)
        int row = tid >> 2, kq = tid & 3;
        const float* src = x + (size_t)(m0 + row) * D_IN + (size_t)(kp + 1) * 32 + kq * 8;
        fa0 = *(const float4*)src;
        fa1 = *(const float4*)(src + 4);
      }
      const unsigned short* wsrc = Wp + (size_t)(kp + 1) * (N1_PAD * 32);
#pragma unroll
      for (int i = 0; i < 3; ++i) {               // B: async global -> LDS
        int chunk = tid + i * 896;
        async_lds16((char*)&Bs[nxt][0] + chunk * 16, (const char*)wsrc + chunk * 16);
      }
    }

    // ---- compute current buffer ----
    short8 af[4], bfr[6];
#pragma unroll
    for (int mi = 0; mi < 4; ++mi)
      af[mi] = *(const short8*)&As[cur][(wr * 64 + mi * 16 + lr) * 32 + lk];
#pragma unroll
    for (int ni = 0; ni < 6; ++ni)
      bfr[ni] = *(const short8*)&Bs[cur][(wc * 96 + ni * 16 + lr) * 32 + lk];
#pragma unroll
    for (int mi = 0; mi < 4; ++mi)
#pragma unroll
      for (int ni = 0; ni < 6; ++ni)
        acc[mi][ni] = __builtin_amdgcn_mfma_f32_16x16x32_bf16(af[mi], bfr[ni], acc[mi][ni], 0, 0, 0);

    if (!last && tid < 512) {                     // A: cvt + reg -> LDS
      int row = tid >> 2, kq = tid & 3;
      *(short8*)&As[nxt][row * 32 + kq * 8] = cvt8(fa0, fa1);
    }
    __syncthreads();
  }

  // ---- epilogue: split cols into scores / deltas / h1 ----
  const int rbase = m0 + wr * 64 + ((lane >> 4) << 2);
#pragma unroll
  for (int mi = 0; mi < 4; ++mi) {
#pragma unroll
    for (int ni = 0; ni < 6; ++ni) {
      int n = wc * 96 + ni * 16 + lr;
      if (n >= N1_USED) continue;
      if (n < N_CLS) {
        float bb = b_cls[n];
#pragma unroll
        for (int j = 0; j < 4; ++j) {
          int r = rbase + mi * 16 + j;
          scores[(size_t)r * N_CLS + n] = acc[mi][ni][j] + bb;
        }
      } else if (n < N_CLS + N_BOX) {
        int nb = n - N_CLS;
        float bb = b_box[nb];
#pragma unroll
        for (int j = 0; j < 4; ++j) {
          int r = rbase + mi * 16 + j;
          deltas[(size_t)r * N_BOX + nb] = acc[mi][ni][j] + bb;
        }
      } else {
        int nh = n - (N_CLS + N_BOX);
        float bb = b1[nh];
#pragma unroll
        for (int j = 0; j < 4; ++j) {
          int r = rbase + mi * 16 + j;
          float h = acc[mi][ni][j] + bb;
          h1[(size_t)r * N_H + nh] = f2bf(fmaxf(h, 0.f));
        }
      }
    }
  }
}

// ---------------- GEMM2/3: full-row blocks, 128(M) x 256(N=all), K=256, BK=32 ----
// 512 threads (8 waves), wave (wm,wn) = (wave>>2, wave&3), per-wave 64x64 output.
// Each block reads ONLY A rows [m0,m0+128) and writes ONLY those rows ->
// in-place (out==A) is block-local and race-free. Grid is (R/128, 1).
__device__ __forceinline__ void g23_stage(unsigned short* Asb, unsigned short* Bsb,
    const unsigned short* __restrict__ A, const unsigned short* __restrict__ Bw,
    int m0, int kp, int tid)
{
  {
    int row = tid >> 2, kq = tid & 3;             // A: 512 chunks of 16B
    async_lds16((char*)Asb + tid * 16,
                (const char*)(A + (size_t)(m0 + row) * N_H + (size_t)kp * 32 + kq * 8));
  }
#pragma unroll
  for (int i = 0; i < 2; ++i) {                   // B: 1024 chunks of 16B
    int chunk = tid + i * 512;
    int row = chunk >> 2, kq = chunk & 3;
    async_lds16((char*)Bsb + chunk * 16,
                (const char*)(Bw + (size_t)row * N_H + (size_t)kp * 32 + kq * 8));
  }
}

template <int RELU, int OUT_BF16>
__global__ __launch_bounds__(512, 1) void g23_kernel(
    const unsigned short* __restrict__ A, const unsigned short* __restrict__ Bw,
    const float* __restrict__ bias, void* __restrict__ outv)
{
  __shared__ __attribute__((aligned(16))) unsigned short As[2][128 * 32];
  __shared__ __attribute__((aligned(16))) unsigned short Bs[2][256 * 32];
  const int tid  = threadIdx.x;
  const int wave = tid >> 6, lane = tid & 63;
  const int wm = wave >> 2, wn = wave & 3;
  const int m0 = blockIdx.x * 128;

  f32x4 acc[4][4];
#pragma unroll
  for (int i = 0; i < 4; ++i)
#pragma unroll
    for (int j = 0; j < 4; ++j)
      acc[i][j] = (f32x4){0.f, 0.f, 0.f, 0.f};

  g23_stage(&As[0][0], &Bs[0][0], A, Bw, m0, 0, tid);
  __syncthreads();

  const int lr = lane & 15;
  const int lk = (lane >> 4) * 8;

  for (int kp = 0; kp < 8; ++kp) {
    const int cur = kp & 1, nxt = cur ^ 1;
    if (kp < 7) g23_stage(&As[nxt][0], &Bs[nxt][0], A, Bw, m0, kp + 1, tid);

    short8 af[4], bfr[4];
#pragma unroll
    for (int mi = 0; mi < 4; ++mi)
      af[mi] = *(const short8*)&As[cur][(wm * 64 + mi * 16 + lr) * 32 + lk];
#pragma unroll
    for (int ni = 0; ni < 4; ++ni)
      bfr[ni] = *(const short8*)&Bs[cur][(wn * 64 + ni * 16 + lr) * 32 + lk];
#pragma unroll
    for (int mi = 0; mi < 4; ++mi)
#pragma unroll
      for (int ni = 0; ni < 4; ++ni)
        acc[mi][ni] = __builtin_amdgcn_mfma_f32_16x16x32_bf16(af[mi], bfr[ni], acc[mi][ni], 0, 0, 0);
    __syncthreads();
  }

  // All LDS reads of A done; safe to overwrite our own rows (even if out==A).
#pragma unroll
  for (int mi = 0; mi < 4; ++mi) {
#pragma unroll
    for (int ni = 0; ni < 4; ++ni) {
      int n = wn * 64 + ni * 16 + lr;
      float bb = bias[n];
#pragma unroll
      for (int j = 0; j < 4; ++j) {
        int r = m0 + wm * 64 + mi * 16 + ((lane >> 4) << 2) + j;
        float v = acc[mi][ni][j] + bb;
        if (RELU) v = fmaxf(v, 0.f);
        if (OUT_BF16) ((unsigned short*)outv)[(size_t)r * N_H + n] = f2bf(v);
        else          ((float*)outv)[(size_t)r * N_H + n] = v;
      }
    }
  }
}

// ---------------- launch ----------------
extern "C" void kernel_launch(void* const* d_in, const int* in_sizes, int n_in,
                              void* d_out, int out_size, void* d_ws, size_t ws_size,
                              hipStream_t stream)
{
  const float* x     = (const float*)d_in[0];
  const float* W_cls = (const float*)d_in[1];
  const float* b_cls = (const float*)d_in[2];
  const float* W_box = (const float*)d_in[3];
  const float* b_box = (const float*)d_in[4];
  const float* W1    = (const float*)d_in[5];
  const float* b1    = (const float*)d_in[6];
  const float* W2    = (const float*)d_in[7];
  const float* b2    = (const float*)d_in[8];
  const float* W3    = (const float*)d_in[9];
  const float* b3    = (const float*)d_in[10];

  float* scores = (float*)d_out;
  float* deltas = scores + (size_t)R_TOT * N_CLS;
  float* embeds = deltas + (size_t)R_TOT * N_BOX;

  // Scratch layout (total ~65.6 MB):
  //   Wp  : 672*1024 bf16      = 1,376,256 B
  //   W2b :  65536 bf16        =   131,072 B
  //   W3b :  65536 bf16        =   131,072 B
  //   h   : 131072*256 bf16    = 67,108,864 B  (h1; GEMM2 overwrites in place -> h2)
  char* ws = (char*)d_ws;
  unsigned short* Wp  = (unsigned short*)ws;
  unsigned short* W2b = (unsigned short*)(ws + 1376256);
  unsigned short* W3b = (unsigned short*)(ws + 1376256 + 131072);
  unsigned short* h   = (unsigned short*)(ws + 1638400);

  hipLaunchKernelGGL(prep_w1, dim3(2688), dim3(256), 0, stream, W_cls, W_box, W1, Wp);
  hipLaunchKernelGGL(prep_w23, dim3(512), dim3(256), 0, stream, W2, W3, W2b, W3b);
  hipLaunchKernelGGL(g1_kernel, dim3(R_TOT / 128), dim3(896), 0, stream,
                     x, Wp, b_cls, b_box, b1, scores, deltas, h);
  hipLaunchKernelGGL((g23_kernel<1, 1>), dim3(R_TOT / 128), dim3(512), 0, stream,
                     h, W2b, b2, (void*)h);       // in place: h1 -> h2 (block-local rows)
  hipLaunchKernelGGL((g23_kernel<0, 0>), dim3(R_TOT / 128), dim3(512), 0, stream,
                     h, W3b, b3, (void*)embeds);
}

// Round 9
// 452.149 us; speedup vs baseline: 1.3015x; 1.3015x over previous
//
#include <hip/hip_runtime.h>
#include <hip/hip_bf16.h>
#include <stdint.h>

#define R_TOT   131072
#define D_IN    1024
#define N_CLS   81
#define N_BOX   320
#define N_H     256
#define N1_USED 657
#define N1_PAD  672
#define NB_COLS 336   // per-block N (half of 672)

typedef __attribute__((ext_vector_type(8))) short short8;
typedef __attribute__((ext_vector_type(4))) float f32x4;

__device__ __forceinline__ unsigned short f2bf(float f) {
  union { float f; unsigned u; } v; v.f = f;
  unsigned r = v.u + 0x7FFFu + ((v.u >> 16) & 1u);
  return (unsigned short)(r >> 16);
}

__device__ __forceinline__ short8 cvt8(float4 a, float4 b) {
  short8 v;
  v[0] = (short)f2bf(a.x); v[1] = (short)f2bf(a.y);
  v[2] = (short)f2bf(a.z); v[3] = (short)f2bf(a.w);
  v[4] = (short)f2bf(b.x); v[5] = (short)f2bf(b.y);
  v[6] = (short)f2bf(b.z); v[7] = (short)f2bf(b.w);
  return v;
}

__device__ __forceinline__ void async_lds16(void* lds, const void* g) {
  __builtin_amdgcn_global_load_lds(
      (const __attribute__((address_space(1))) unsigned int*)g,
      (__attribute__((address_space(3))) unsigned int*)lds, 16, 0, 0);
}

// ---------------- prep: pack W_big into K-panels [32][672][32] bf16 ----------------
__global__ void prep_w1(const float* __restrict__ Wc, const float* __restrict__ Wb,
                        const float* __restrict__ W1, unsigned short* __restrict__ Wp)
{
  int idx = blockIdx.x * 256 + threadIdx.x;      // < 672*1024
  int p   = idx / (N1_PAD * 32);
  int rem = idx % (N1_PAD * 32);
  int n   = rem >> 5;
  int kk  = rem & 31;
  int k   = p * 32 + kk;
  float w = 0.f;
  if (n < N_CLS)               w = Wc[(size_t)n * D_IN + k];
  else if (n < N_CLS + N_BOX)  w = Wb[(size_t)(n - N_CLS) * D_IN + k];
  else if (n < N1_USED)        w = W1[(size_t)(n - (N_CLS + N_BOX)) * D_IN + k];
  Wp[idx] = f2bf(w);
}

__global__ void prep_w23(const float* __restrict__ W2, const float* __restrict__ W3,
                         unsigned short* __restrict__ W2b, unsigned short* __restrict__ W3b)
{
  int idx = blockIdx.x * 256 + threadIdx.x;      // < 131072
  if (idx < 65536) W2b[idx] = f2bf(W2[idx]);
  else             W3b[idx - 65536] = f2bf(W3[idx - 65536]);
}

// ---------------- GEMM1: 64(M) x 336(N) per block, K=1024 ----------------
// Grid 4096 = 2048 M-tiles x 2 N-halves. 448 threads (7 waves); wave wc owns
// cols [wc*48, wc*48+48). LDS 51.2 KB -> up to 3 blocks/CU co-resident:
// independent blocks overlap each other's barrier/vmcnt drains (m114 mechanism).
// XCD-chunk swizzle keeps an M-tile's two N-halves temporally adjacent on one
// XCD so the second read of x hits L2/L3 instead of HBM.
__global__ __launch_bounds__(448, 6) void g1_kernel(
    const float* __restrict__ x, const unsigned short* __restrict__ Wp,
    const float* __restrict__ b_cls, const float* __restrict__ b_box,
    const float* __restrict__ b1,
    float* __restrict__ scores, float* __restrict__ deltas,
    unsigned short* __restrict__ h1)
{
  __shared__ __attribute__((aligned(16))) unsigned short As[2][64 * 32];       // 8 KB
  __shared__ __attribute__((aligned(16))) unsigned short Bs[2][NB_COLS * 32];  // 43 KB

  const int tid  = threadIdx.x;
  const int wave = tid >> 6;
  const int lane = tid & 63;
  // bijective XCD-chunk swizzle (nwg = 4096, 4096 % 8 == 0)
  const int orig  = blockIdx.x;
  const int work  = (orig & 7) * 512 + (orig >> 3);
  const int m0    = (work >> 1) * 64;
  const int nbase = (work & 1) * NB_COLS;

  f32x4 acc[4][3];
#pragma unroll
  for (int i = 0; i < 4; ++i)
#pragma unroll
    for (int j = 0; j < 3; ++j)
      acc[i][j] = (f32x4){0.f, 0.f, 0.f, 0.f};

  // ---- prologue: stage k-step 0 into buffer 0 ----
  {
    const unsigned short* wsrc = Wp + (size_t)nbase * 32;
#pragma unroll
    for (int i = 0; i < 3; ++i) {
      int chunk = tid + i * 448;                 // 0..1343 (336*32*2B / 16B)
      async_lds16((char*)&Bs[0][0] + chunk * 16, (const char*)wsrc + chunk * 16);
    }
    if (tid < 256) {
      int row = tid >> 2, kq = tid & 3;
      const float* src = x + (size_t)(m0 + row) * D_IN + kq * 8;
      float4 f0 = *(const float4*)src;
      float4 f1 = *(const float4*)(src + 4);
      *(short8*)&As[0][row * 32 + kq * 8] = cvt8(f0, f1);
    }
  }
  __syncthreads();

  const int lr = lane & 15;
  const int lk = (lane >> 4) * 8;

  for (int kp = 0; kp < 32; ++kp) {
    const int cur = kp & 1;
    const int nxt = cur ^ 1;
    const bool last = (kp == 31);

    float4 fa0, fa1;
    if (!last) {
      if (tid < 256) {                            // A: global -> reg (fp32)
        int row = tid >> 2, kq = tid & 3;
        const float* src = x + (size_t)(m0 + row) * D_IN + (size_t)(kp + 1) * 32 + kq * 8;
        fa0 = *(const float4*)src;
        fa1 = *(const float4*)(src + 4);
      }
      const unsigned short* wsrc = Wp + (size_t)(kp + 1) * (N1_PAD * 32) + (size_t)nbase * 32;
#pragma unroll
      for (int i = 0; i < 3; ++i) {               // B: async global -> LDS
        int chunk = tid + i * 448;
        async_lds16((char*)&Bs[nxt][0] + chunk * 16, (const char*)wsrc + chunk * 16);
      }
    }

    // ---- compute current buffer ----
    short8 af[4], bfr[3];
#pragma unroll
    for (int mi = 0; mi < 4; ++mi)
      af[mi] = *(const short8*)&As[cur][(mi * 16 + lr) * 32 + lk];
#pragma unroll
    for (int ni = 0; ni < 3; ++ni)
      bfr[ni] = *(const short8*)&Bs[cur][(wave * 48 + ni * 16 + lr) * 32 + lk];
#pragma unroll
    for (int mi = 0; mi < 4; ++mi)
#pragma unroll
      for (int ni = 0; ni < 3; ++ni)
        acc[mi][ni] = __builtin_amdgcn_mfma_f32_16x16x32_bf16(af[mi], bfr[ni], acc[mi][ni], 0, 0, 0);

    if (!last && tid < 256) {                     // A: cvt + reg -> LDS
      int row = tid >> 2, kq = tid & 3;
      *(short8*)&As[nxt][row * 32 + kq * 8] = cvt8(fa0, fa1);
    }
    __syncthreads();
  }

  // ---- epilogue: split cols into scores / deltas / h1 ----
  const int rbase = m0 + ((lane >> 4) << 2);
#pragma unroll
  for (int mi = 0; mi < 4; ++mi) {
#pragma unroll
    for (int ni = 0; ni < 3; ++ni) {
      int n = nbase + wave * 48 + ni * 16 + lr;
      if (n >= N1_USED) continue;
      if (n < N_CLS) {
        float bb = b_cls[n];
#pragma unroll
        for (int j = 0; j < 4; ++j) {
          int r = rbase + mi * 16 + j;
          scores[(size_t)r * N_CLS + n] = acc[mi][ni][j] + bb;
        }
      } else if (n < N_CLS + N_BOX) {
        int nb = n - N_CLS;
        float bb = b_box[nb];
#pragma unroll
        for (int j = 0; j < 4; ++j) {
          int r = rbase + mi * 16 + j;
          deltas[(size_t)r * N_BOX + nb] = acc[mi][ni][j] + bb;
        }
      } else {
        int nh = n - (N_CLS + N_BOX);
        float bb = b1[nh];
#pragma unroll
        for (int j = 0; j < 4; ++j) {
          int r = rbase + mi * 16 + j;
          float h = acc[mi][ni][j] + bb;
          h1[(size_t)r * N_H + nh] = f2bf(fmaxf(h, 0.f));
        }
      }
    }
  }
}

// ---------------- GEMM2/3: full-row blocks, 128(M) x 256(N=all), K=256, BK=32 ----
// 512 threads (8 waves), wave (wm,wn) = (wave>>2, wave&3), per-wave 64x64 output.
// Each block reads ONLY A rows [m0,m0+128) and writes ONLY those rows ->
// in-place (out==A) is block-local and race-free. Grid is (R/128, 1).
__device__ __forceinline__ void g23_stage(unsigned short* Asb, unsigned short* Bsb,
    const unsigned short* __restrict__ A, const unsigned short* __restrict__ Bw,
    int m0, int kp, int tid)
{
  {
    int row = tid >> 2, kq = tid & 3;             // A: 512 chunks of 16B
    async_lds16((char*)Asb + tid * 16,
                (const char*)(A + (size_t)(m0 + row) * N_H + (size_t)kp * 32 + kq * 8));
  }
#pragma unroll
  for (int i = 0; i < 2; ++i) {                   // B: 1024 chunks of 16B
    int chunk = tid + i * 512;
    int row = chunk >> 2, kq = chunk & 3;
    async_lds16((char*)Bsb + chunk * 16,
                (const char*)(Bw + (size_t)row * N_H + (size_t)kp * 32 + kq * 8));
  }
}

template <int RELU, int OUT_BF16>
__global__ __launch_bounds__(512, 1) void g23_kernel(
    const unsigned short* __restrict__ A, const unsigned short* __restrict__ Bw,
    const float* __restrict__ bias, void* __restrict__ outv)
{
  __shared__ __attribute__((aligned(16))) unsigned short As[2][128 * 32];
  __shared__ __attribute__((aligned(16))) unsigned short Bs[2][256 * 32];
  const int tid  = threadIdx.x;
  const int wave = tid >> 6, lane = tid & 63;
  const int wm = wave >> 2, wn = wave & 3;
  const int m0 = blockIdx.x * 128;

  f32x4 acc[4][4];
#pragma unroll
  for (int i = 0; i < 4; ++i)
#pragma unroll
    for (int j = 0; j < 4; ++j)
      acc[i][j] = (f32x4){0.f, 0.f, 0.f, 0.f};

  g23_stage(&As[0][0], &Bs[0][0], A, Bw, m0, 0, tid);
  __syncthreads();

  const int lr = lane & 15;
  const int lk = (lane >> 4) * 8;

  for (int kp = 0; kp < 8; ++kp) {
    const int cur = kp & 1, nxt = cur ^ 1;
    if (kp < 7) g23_stage(&As[nxt][0], &Bs[nxt][0], A, Bw, m0, kp + 1, tid);

    short8 af[4], bfr[4];
#pragma unroll
    for (int mi = 0; mi < 4; ++mi)
      af[mi] = *(const short8*)&As[cur][(wm * 64 + mi * 16 + lr) * 32 + lk];
#pragma unroll
    for (int ni = 0; ni < 4; ++ni)
      bfr[ni] = *(const short8*)&Bs[cur][(wn * 64 + ni * 16 + lr) * 32 + lk];
#pragma unroll
    for (int mi = 0; mi < 4; ++mi)
#pragma unroll
      for (int ni = 0; ni < 4; ++ni)
        acc[mi][ni] = __builtin_amdgcn_mfma_f32_16x16x32_bf16(af[mi], bfr[ni], acc[mi][ni], 0, 0, 0);
    __syncthreads();
  }

  // All LDS reads of A done; safe to overwrite our own rows (even if out==A).
#pragma unroll
  for (int mi = 0; mi < 4; ++mi) {
#pragma unroll
    for (int ni = 0; ni < 4; ++ni) {
      int n = wn * 64 + ni * 16 + lr;
      float bb = bias[n];
#pragma unroll
      for (int j = 0; j < 4; ++j) {
        int r = m0 + wm * 64 + mi * 16 + ((lane >> 4) << 2) + j;
        float v = acc[mi][ni][j] + bb;
        if (RELU) v = fmaxf(v, 0.f);
        if (OUT_BF16) ((unsigned short*)outv)[(size_t)r * N_H + n] = f2bf(v);
        else          ((float*)outv)[(size_t)r * N_H + n] = v;
      }
    }
  }
}

// ---------------- launch ----------------
extern "C" void kernel_launch(void* const* d_in, const int* in_sizes, int n_in,
                              void* d_out, int out_size, void* d_ws, size_t ws_size,
                              hipStream_t stream)
{
  const float* x     = (const float*)d_in[0];
  const float* W_cls = (const float*)d_in[1];
  const float* b_cls = (const float*)d_in[2];
  const float* W_box = (const float*)d_in[3];
  const float* b_box = (const float*)d_in[4];
  const float* W1    = (const float*)d_in[5];
  const float* b1    = (const float*)d_in[6];
  const float* W2    = (const float*)d_in[7];
  const float* b2    = (const float*)d_in[8];
  const float* W3    = (const float*)d_in[9];
  const float* b3    = (const float*)d_in[10];

  float* scores = (float*)d_out;
  float* deltas = scores + (size_t)R_TOT * N_CLS;
  float* embeds = deltas + (size_t)R_TOT * N_BOX;

  // Scratch layout (total ~65.6 MB):
  //   Wp  : 672*1024 bf16      = 1,376,256 B
  //   W2b :  65536 bf16        =   131,072 B
  //   W3b :  65536 bf16        =   131,072 B
  //   h   : 131072*256 bf16    = 67,108,864 B  (h1; GEMM2 overwrites in place -> h2)
  char* ws = (char*)d_ws;
  unsigned short* Wp  = (unsigned short*)ws;
  unsigned short* W2b = (unsigned short*)(ws + 1376256);
  unsigned short* W3b = (unsigned short*)(ws + 1376256 + 131072);
  unsigned short* h   = (unsigned short*)(ws + 1638400);

  hipLaunchKernelGGL(prep_w1, dim3(2688), dim3(256), 0, stream, W_cls, W_box, W1, Wp);
  hipLaunchKernelGGL(prep_w23, dim3(512), dim3(256), 0, stream, W2, W3, W2b, W3b);
  hipLaunchKernelGGL(g1_kernel, dim3(4096), dim3(448), 0, stream,
                     x, Wp, b_cls, b_box, b1, scores, deltas, h);
  hipLaunchKernelGGL((g23_kernel<1, 1>), dim3(R_TOT / 128), dim3(512), 0, stream,
                     h, W2b, b2, (void*)h);       // in place: h1 -> h2 (block-local rows)
  hipLaunchKernelGGL((g23_kernel<0, 0>), dim3(R_TOT / 128), dim3(512), 0, stream,
                     h, W3b, b3, (void*)embeds);
}